// Round 5
// baseline (182.677 us; speedup 1.0000x reference)
//
#include <hip/hip_runtime.h>

#define BDIM 256

constexpr int Vv = 3, Cc = 64, Hh = 96, Ww = 96, Dd = 48;
constexpr int HW = Hh * Ww;          // 9216
constexpr int NPIX = Dd * HW;        // 442368
constexpr int DHW = Dd * HW;         // output channel stride
constexpr int TSTR = 100;            // s_tile row stride (400 B: 16B-aligned, bank-staggered)

typedef float f32x4 __attribute__((ext_vector_type(4)));   // native vec for nontemporal builtins

// ---------------------------------------------------------------------------
// Shared coordinate/weight computation (identical numerics since round 1).
// ---------------------------------------------------------------------------
__device__ __forceinline__ void compute_warp(const float* __restrict__ proj, float depth,
                                             float xf, float yf,
                                             int offs[2][4], float wts[2][4], float& msum)
{
    msum = 1.0f;
#pragma unroll
    for (int v = 0; v < 2; ++v) {
#pragma clang fp contract(off)
        const float* P = proj + (v + 1) * 12;
        const float r00 = P[0], r01 = P[1], r02 = P[2],  t0 = P[3];
        const float r10 = P[4], r11 = P[5], r12 = P[6],  t1 = P[7];
        const float r20 = P[8], r21 = P[9], r22 = P[10], t2 = P[11];

        const float px = ((r00 * xf + r01 * yf) + r02) + t0 / depth;
        const float py = ((r10 * xf + r11 * yf) + r12) + t1 / depth;
        const float pz = ((r20 * xf + r21 * yf) + r22) + t2 / depth;

        const float xy0 = px / pz;
        const float xy1 = py / pz;
        const float gx = xy0 / ((float)(Ww - 1) * 0.5f) - 1.0f;
        const float gy = xy1 / ((float)(Hh - 1) * 0.5f) - 1.0f;

        const bool inb = (gx > -1.0f) && (gx < 1.0f) && (gy > -1.0f) && (gy < 1.0f);
        msum += inb ? 1.0f : 0.0f;

        const float sx = (gx + 1.0f) * 0.5f * (float)(Ww - 1);
        const float sy = (gy + 1.0f) * 0.5f * (float)(Hh - 1);
        const float x0 = floorf(sx), y0 = floorf(sy);
        const float wx1 = sx - x0, wy1 = sy - y0;
        const float wx0 = 1.0f - wx1, wy0 = 1.0f - wy1;

#pragma unroll
        for (int k = 0; k < 4; ++k) {
            const float xi = (k & 1) ? (x0 + 1.0f) : x0;
            const float yi = (k & 2) ? (y0 + 1.0f) : y0;
            const float wk = ((k & 1) ? wx1 : wx0) * ((k & 2) ? wy1 : wy0);
            const bool valid = (xi >= 0.0f) && (xi <= (float)(Ww - 1)) &&
                               (yi >= 0.0f) && (yi <= (float)(Hh - 1));
            const float xc = fminf(fmaxf(xi, 0.0f), (float)(Ww - 1));
            const float yc = fminf(fmaxf(yi, 0.0f), (float)(Hh - 1));
            offs[v][k] = (int)yc * Ww + (int)xc;
            wts[v][k] = valid ? wk : 0.0f;
        }
    }
}

// ---------------------------------------------------------------------------
// feats (V, C, HW) -> ftr (V, HW, C)  (channel-minor). Source is dead after
// this pass -> non-temporal loads keep it out of L2.
// ---------------------------------------------------------------------------
__global__ void __launch_bounds__(BDIM) transpose_feats_kernel(const float* __restrict__ feats,
                                                               float* __restrict__ ft)
{
    __shared__ float tile[64][65];
    const int v  = blockIdx.y;
    const int p0 = blockIdx.x * 64;
    const float* src = feats + (size_t)v * Cc * HW;

    const int px = threadIdx.x & 63;
    const int c0 = threadIdx.x >> 6;
#pragma unroll
    for (int c = c0; c < Cc; c += 4)
        tile[c][px] = __builtin_nontemporal_load(&src[(size_t)c * HW + p0 + px]);
    __syncthreads();

    const int cc  = threadIdx.x & 63;
    const int pr0 = threadIdx.x >> 6;
    float* dst = ft + ((size_t)v * HW + p0) * Cc;
#pragma unroll
    for (int p = pr0; p < 64; p += 4)
        dst[p * Cc + cc] = tile[cc][p];
}

// ---------------------------------------------------------------------------
// main kernel: one block per (d, h) row of 96 pixels.
// Phase 1: 96 threads compute warp coords -> LDS; img channels (0..8) stored.
// Phase 2: wave handles 24 pixels; 16 lanes/pixel x float4 = 4 px/group,
//          9 coalesced 1KB dwordx4 gathers per group of 4 pixels.
// Phase 3: variance tile LDS -> dwordx4 non-temporal coalesced stores.
// ---------------------------------------------------------------------------
__global__ void __launch_bounds__(BDIM) ge_row_kernel(
    const float* __restrict__ imgs, const float* __restrict__ ftr,
    const float* __restrict__ proj, const float* __restrict__ depthv,
    float* __restrict__ out)
{
    __shared__ float  s_tile[Cc][TSTR];      // 25.6 KB
    __shared__ float2 s_bw[2][4][Ww];        // (base index bits, weight) 6.0 KB
    __shared__ float  s_cnt[Ww];

    const int blk = blockIdx.x;              // d*Hh + h
    const int d   = blk / Hh;
    const int h   = blk % Hh;
    const int tid = threadIdx.x;
    const int rowbase = d * HW + h * Ww;

    // ---- Phase 1 ----
    if (tid < Ww) {
        const int w = tid;
        int offs[2][4];
        float wts[2][4];
        float msum;
        compute_warp(proj, depthv[d], (float)w, (float)h, offs, wts, msum);
        s_cnt[w] = 1.0f / msum;
#pragma unroll
        for (int v = 0; v < 2; ++v)
#pragma unroll
            for (int k = 0; k < 4; ++k) {
                const int base = ((v + 1) * HW + offs[v][k]) * Cc;
                s_bw[v][k][w] = make_float2(__int_as_float(base), wts[v][k]);
            }

        const int hw = h * Ww + w;
#pragma unroll
        for (int c = 0; c < 3; ++c)
            __builtin_nontemporal_store(imgs[c * HW + hw], &out[c * DHW + rowbase + w]);

#pragma unroll
        for (int v = 0; v < 2; ++v) {
            const float* ib = imgs + (size_t)(v + 1) * 3 * HW;
#pragma unroll
            for (int c = 0; c < 3; ++c) {
                const float* p = ib + (size_t)c * HW;
                const float acc = wts[v][0] * p[offs[v][0]] + wts[v][1] * p[offs[v][1]] +
                                  wts[v][2] * p[offs[v][2]] + wts[v][3] * p[offs[v][3]];
                __builtin_nontemporal_store(acc, &out[(3 * (v + 1) + c) * DHW + rowbase + w]);
            }
        }
    }
    __syncthreads();

    // ---- Phase 2 ----
    {
        const int wave = tid >> 6;
        const int lane = tid & 63;
        const int sub  = lane >> 4;          // pixel within group of 4
        const int cq   = lane & 15;          // channel quad
        const int c4   = 4 * cq;
        const float* ftr0 = ftr + (size_t)(h * Ww) * Cc;  // view-0 row base

#pragma unroll 2
        for (int g = 0; g < 6; ++g) {
            const int p = wave * 24 + g * 4 + sub;
            const float cnt = s_cnt[p];
            const float2 bw00 = s_bw[0][0][p], bw01 = s_bw[0][1][p];
            const float2 bw02 = s_bw[0][2][p], bw03 = s_bw[0][3][p];
            const float2 bw10 = s_bw[1][0][p], bw11 = s_bw[1][1][p];
            const float2 bw12 = s_bw[1][2][p], bw13 = s_bw[1][3][p];

            const float4 fr  = *(const float4*)(ftr0 + (size_t)p * Cc + c4);
            const float4 v00 = *(const float4*)(ftr + (size_t)__float_as_int(bw00.x) + c4);
            const float4 v01 = *(const float4*)(ftr + (size_t)__float_as_int(bw01.x) + c4);
            const float4 v02 = *(const float4*)(ftr + (size_t)__float_as_int(bw02.x) + c4);
            const float4 v03 = *(const float4*)(ftr + (size_t)__float_as_int(bw03.x) + c4);
            const float4 v10 = *(const float4*)(ftr + (size_t)__float_as_int(bw10.x) + c4);
            const float4 v11 = *(const float4*)(ftr + (size_t)__float_as_int(bw11.x) + c4);
            const float4 v12 = *(const float4*)(ftr + (size_t)__float_as_int(bw12.x) + c4);
            const float4 v13 = *(const float4*)(ftr + (size_t)__float_as_int(bw13.x) + c4);

            const float w00 = bw00.y, w01 = bw01.y, w02 = bw02.y, w03 = bw03.y;
            const float w10 = bw10.y, w11 = bw11.y, w12 = bw12.y, w13 = bw13.y;

            float var_[4];
#define VARC(comp, j)                                                            \
            {                                                                    \
                const float A_ = w00 * v00.comp + w01 * v01.comp +               \
                                 w02 * v02.comp + w03 * v03.comp;                \
                const float B_ = w10 * v10.comp + w11 * v11.comp +               \
                                 w12 * v12.comp + w13 * v13.comp;                \
                const float F_ = fr.comp;                                        \
                const float S_ = F_ + A_ + B_;                                   \
                const float Q_ = F_ * F_ + A_ * A_ + B_ * B_;                    \
                const float sc_ = S_ * cnt;                                      \
                var_[j] = Q_ * cnt - sc_ * sc_;                                  \
            }
            VARC(x, 0) VARC(y, 1) VARC(z, 2) VARC(w, 3)
#undef VARC
            // rotated column order -> 4-way banks instead of 8-way
#pragma unroll
            for (int jj = 0; jj < 4; ++jj) {
                const int col = (jj + cq) & 3;
                s_tile[c4 + col][p] = var_[col];
            }
        }
    }
    __syncthreads();

    // ---- Phase 3 ----  64 channels x 24 float4 = 1536 stores / 256 threads
#pragma unroll
    for (int i = 0; i < 6; ++i) {
        const int idx = i * BDIM + tid;
        const int c   = idx / 24;
        const int pp  = idx - c * 24;
        const f32x4 vv = *(const f32x4*)&s_tile[c][pp * 4];
        f32x4* dst = (f32x4*)(out + (size_t)(9 + c) * DHW + rowbase + pp * 4);
        __builtin_nontemporal_store(vv, dst);
    }
}

// ---------------------------------------------------------------------------
// fallback (no workspace needed) — only used if ws_size is too small
// ---------------------------------------------------------------------------
__global__ void __launch_bounds__(BDIM) ge_direct_kernel(
    const float* __restrict__ imgs, const float* __restrict__ feats,
    const float* __restrict__ proj, const float* __restrict__ depthv,
    float* __restrict__ out)
{
    const int idx = blockIdx.x * BDIM + threadIdx.x;
    if (idx >= NPIX) return;
    const int w = idx % Ww;
    const int t = idx / Ww;
    const int h = t % Hh;
    const int d = t / Hh;
    const int ohw = h * Ww + w;

    int offs[2][4];
    float wts[2][4];
    float msum;
    compute_warp(proj, depthv[d], (float)w, (float)h, offs, wts, msum);

    const int obase = d * HW + ohw;
#pragma unroll
    for (int c = 0; c < 3; ++c)
        out[c * DHW + obase] = imgs[c * HW + ohw];

#pragma unroll
    for (int v = 0; v < 2; ++v) {
        const float* ib = imgs + (size_t)(v + 1) * 3 * HW;
#pragma unroll
        for (int c = 0; c < 3; ++c) {
            const float* p = ib + (size_t)c * HW;
            const float acc = wts[v][0] * p[offs[v][0]] + wts[v][1] * p[offs[v][1]] +
                              wts[v][2] * p[offs[v][2]] + wts[v][3] * p[offs[v][3]];
            out[(3 * (v + 1) + c) * DHW + obase] = acc;
        }
    }

    const float count = 1.0f / msum;
    const float* f0 = feats;
    const float* f1 = feats + (size_t)Cc * HW;
    const float* f2 = feats + (size_t)2 * Cc * HW;
#pragma unroll 8
    for (int c = 0; c < Cc; ++c) {
        const float fr = f0[(size_t)c * HW + ohw];
        const float* p1 = f1 + (size_t)c * HW;
        const float* p2 = f2 + (size_t)c * HW;
        const float a1 = wts[0][0] * p1[offs[0][0]] + wts[0][1] * p1[offs[0][1]] +
                         wts[0][2] * p1[offs[0][2]] + wts[0][3] * p1[offs[0][3]];
        const float a2 = wts[1][0] * p2[offs[1][0]] + wts[1][1] * p2[offs[1][1]] +
                         wts[1][2] * p2[offs[1][2]] + wts[1][3] * p2[offs[1][3]];
        const float s = fr + a1 + a2;
        const float sq = fr * fr + a1 * a1 + a2 * a2;
        const float sc = s * count;
        out[(3 * Vv + c) * DHW + obase] = sq * count - sc * sc;
    }
}

extern "C" void kernel_launch(void* const* d_in, const int* in_sizes, int n_in,
                              void* d_out, int out_size, void* d_ws, size_t ws_size,
                              hipStream_t stream)
{
    const float* imgs   = (const float*)d_in[0];
    const float* feats  = (const float*)d_in[1];
    const float* proj   = (const float*)d_in[2];
    const float* depthv = (const float*)d_in[3];
    float* out = (float*)d_out;

    const size_t need = (size_t)Vv * HW * Cc * sizeof(float);   // 7.08 MB

    if (ws_size >= need) {
        float* ftr = (float*)d_ws;
        dim3 g1(HW / 64, Vv);
        transpose_feats_kernel<<<g1, BDIM, 0, stream>>>(feats, ftr);
        ge_row_kernel<<<Dd * Hh, BDIM, 0, stream>>>(imgs, ftr, proj, depthv, out);
    } else {
        const int blocks = (NPIX + BDIM - 1) / BDIM;
        ge_direct_kernel<<<blocks, BDIM, 0, stream>>>(imgs, feats, proj, depthv, out);
    }
}